// Round 4
// baseline (77.434 us; speedup 1.0000x reference)
//
#include <hip/hip_runtime.h>
#include <hip/hip_bf16.h>

#define NC 20
#define NCELL 49
#define NGT 32
#define NIMG 8192
#define IPB 8                      // images per block
#define CPB (IPB * NCELL)          // 392 cells per block
#define NBLK (NIMG / IPB)          // 1024 blocks = exactly 4 per CU
#define LAMBDA_COORD 5.0f
#define LAMBDA_NOOBJ 0.5f
#define EPS_IOU 1e-6f

// Divide-free IoU argmax via S-form: S = pa + ga + eps; comparing in/S is a
// monotone transform of iou = in/(S - in). Init (-1, 1) => j=0 always wins,
// strict > thereafter => first-index argmax (jnp semantics).
#define UPD(g, ga_, j_) do {                                          \
    float iw0 = fmaxf(fminf(px2_0, (g).z) - fmaxf(px1_0, (g).x), 0.f);\
    float ih0 = fmaxf(fminf(py2_0, (g).w) - fmaxf(py1_0, (g).y), 0.f);\
    float in0 = iw0 * ih0;                                            \
    float S0  = pa0e + (ga_);                                         \
    if (in0 * bS0 > bin0 * S0) { bin0 = in0; bS0 = S0; bi0 = (j_); }  \
    float iw1 = fmaxf(fminf(px2_1, (g).z) - fmaxf(px1_1, (g).x), 0.f);\
    float ih1 = fmaxf(fminf(py2_1, (g).w) - fmaxf(py1_1, (g).y), 0.f);\
    float in1 = iw1 * ih1;                                            \
    float S1  = pa1e + (ga_);                                         \
    if (in1 * bS1 > bin1 * S1) { bin1 = in1; bS1 = S1; bi1 = (j_); }  \
} while (0)

__global__ __launch_bounds__(256, 4) void yolo_main_kernel(
    const float* __restrict__ outputs,     // [N, 49, 30]
    const float* __restrict__ gt_boxes,    // [N, 32, 4]
    const int*   __restrict__ gt_labels,   // [N, 32]
    float* __restrict__ out)               // [1]
{
    __shared__ float4   s_act4[1920];      // 30720 B: one pass worth (256 cells)
    __shared__ float4   s_gtc[IPB * NGT];  //  4096 B: x1,y1,x2,y2 per GT
    __shared__ float    s_ga[IPB * NGT];   //  1024 B: area per GT
    __shared__ unsigned s_mask[IPB];
    __shared__ float    s_w[4];

    const int tid = threadIdx.x;

    if (tid < IPB) s_mask[tid] = 0u;
    __syncthreads();

    // ---- stage GT: exactly one record per thread (8 img x 32 gt = 256) ----
    {
        float4 b = reinterpret_cast<const float4*>(gt_boxes)[(size_t)blockIdx.x * 256 + tid];
        s_gtc[tid] = make_float4(fmaf(b.z, -0.5f, b.x), fmaf(b.w, -0.5f, b.y),
                                 fmaf(b.z,  0.5f, b.x), fmaf(b.w,  0.5f, b.y));
        s_ga[tid] = b.z * b.w;
        int lab = gt_labels[(size_t)blockIdx.x * 256 + tid];
        atomicOr(&s_mask[tid >> 5], 1u << lab);
    }

    const float4* asrc = reinterpret_cast<const float4*>(outputs) + (size_t)blockIdx.x * (CPB * 30 / 4);

    // ---- stage activations pass 1: cells 0..255 (1920 float4, coalesced) ----
    #pragma unroll
    for (int k = 0; k < 8; ++k) {
        int i = tid + k * 256;
        if (i < 1920) s_act4[i] = asrc[i];
    }
    __syncthreads();

    // per-(slot, cell) loss; reads s_act4[slot], GT tables for image c/49
    auto cell_loss = [&](int slot, int c) -> float {
        const unsigned rel  = ((unsigned)c * 1339u) >> 16;   // c/49 for c<392
        const unsigned mask = s_mask[rel];
        const float2* a2 = reinterpret_cast<const float2*>(s_act4) + slot * 15;

        // CE first so class registers die before the box loop
        float cls[NC];
        #pragma unroll
        for (int k = 0; k < 10; ++k) {
            float2 v = a2[5 + k];
            cls[2 * k] = v.x; cls[2 * k + 1] = v.y;
        }
        float mx0 = cls[0];
        #pragma unroll
        for (int cc = 1; cc < NC; ++cc) mx0 = fmaxf(mx0, cls[cc]);
        float ssum = 0.f;
        #pragma unroll
        for (int cc = 0; cc < NC; ++cc) ssum += __expf(cls[cc] - mx0);
        const float lse = mx0 + __logf(ssum);
        float sel = 0.f;
        #pragma unroll
        for (int cc = 0; cc < NC; ++cc)
            if ((mask >> cc) & 1u) sel += cls[cc];
        const float ce = (float)__popc(mask) * lse - sel;

        // box registers
        float2 q0 = a2[0], q1 = a2[1], q2 = a2[2], q3 = a2[3], q4 = a2[4];
        const float cx0 = q0.x, cy0 = q0.y, w0 = q1.x, h0 = q1.y, cf0 = q2.x;
        const float cx1 = q2.y, cy1 = q3.x, w1 = q3.y, h1 = q4.x, cf1 = q4.y;
        const float px1_0 = fmaf(w0, -0.5f, cx0), py1_0 = fmaf(h0, -0.5f, cy0);
        const float px2_0 = fmaf(w0,  0.5f, cx0), py2_0 = fmaf(h0,  0.5f, cy0);
        const float px1_1 = fmaf(w1, -0.5f, cx1), py1_1 = fmaf(h1, -0.5f, cy1);
        const float px2_1 = fmaf(w1,  0.5f, cx1), py2_1 = fmaf(h1,  0.5f, cy1);
        const float pa0e = w0 * h0 + EPS_IOU, pa1e = w1 * h1 + EPS_IOU;

        const float4* gtc = s_gtc + rel * NGT;
        const float*  gab = s_ga  + rel * NGT;
        float bin0 = -1.f, bS0 = 1.f, bin1 = -1.f, bS1 = 1.f;
        int bi0 = 0, bi1 = 0;
        #pragma unroll
        for (int jc = 0; jc < NGT; jc += 4) {
            float4 g0 = gtc[jc], g1 = gtc[jc + 1], g2 = gtc[jc + 2], g3 = gtc[jc + 3];
            float4 ar = *reinterpret_cast<const float4*>(gab + jc);
            UPD(g0, ar.x, jc);
            UPD(g1, ar.y, jc + 1);
            UPD(g2, ar.z, jc + 2);
            UPD(g3, ar.w, jc + 3);
        }

        // epilogue: recover matched cx/cy/w/h from corners
        float term0, term1;
        if (bin0 > 0.f) {
            float4 g = gtc[bi0];
            const float iou = __fdividef(bin0, bS0 - bin0);
            const float dx = cx0 - (g.x + g.z) * 0.5f, dy = cy0 - (g.y + g.w) * 0.5f;
            const float dw = sqrtf(w0) - sqrtf(g.z - g.x);
            const float dh = sqrtf(h0) - sqrtf(g.w - g.y);
            term0 = LAMBDA_COORD * (dx * dx + dy * dy + dw * dw + dh * dh)
                  + (cf0 - iou) * (cf0 - iou) + ce;
        } else {
            term0 = LAMBDA_NOOBJ * cf0 * cf0;
        }
        if (bin1 > 0.f) {
            float4 g = gtc[bi1];
            const float iou = __fdividef(bin1, bS1 - bin1);
            const float dx = cx1 - (g.x + g.z) * 0.5f, dy = cy1 - (g.y + g.w) * 0.5f;
            const float dw = sqrtf(w1) - sqrtf(g.z - g.x);
            const float dh = sqrtf(h1) - sqrtf(g.w - g.y);
            term1 = LAMBDA_COORD * (dx * dx + dy * dy + dw * dw + dh * dh)
                  + (cf1 - iou) * (cf1 - iou) + ce;
        } else {
            term1 = LAMBDA_NOOBJ * cf1 * cf1;
        }
        return term0 + term1;
    };

    float partial = cell_loss(tid, tid);          // pass 1: all 256 threads
    __syncthreads();                              // done reading s_act4

    // ---- stage activations pass 2: cells 256..391 (1020 float4) ----
    #pragma unroll
    for (int k = 0; k < 4; ++k) {
        int i = tid + k * 256;
        if (i < (CPB - 256) * 30 / 4) s_act4[i] = asrc[1920 + i];
    }
    __syncthreads();

    if (tid < CPB - 256) partial += cell_loss(tid, 256 + tid);

    // ---- block reduce -> one atomic per block ----
    #pragma unroll
    for (int off = 32; off > 0; off >>= 1)
        partial += __shfl_down(partial, off);
    if ((tid & 63) == 0) s_w[tid >> 6] = partial;
    __syncthreads();
    if (tid == 0)
        atomicAdd(out, (s_w[0] + s_w[1] + s_w[2] + s_w[3]) * (1.0f / (float)NIMG));
}

extern "C" void kernel_launch(void* const* d_in, const int* in_sizes, int n_in,
                              void* d_out, int out_size, void* d_ws, size_t ws_size,
                              hipStream_t stream) {
    const float* outputs   = (const float*)d_in[0];
    const float* gt_boxes  = (const float*)d_in[1];
    const int*   gt_labels = (const int*)d_in[2];
    float* out = (float*)d_out;

    hipMemsetAsync(out, 0, sizeof(float), stream);
    yolo_main_kernel<<<NBLK, 256, 0, stream>>>(outputs, gt_boxes, gt_labels, out);
}